// Round 5
// baseline (1085.416 us; speedup 1.0000x reference)
//
#include <hip/hip_runtime.h>

// UAG_RNN v5: raw s_barrier (lgkmcnt-only, loads stay in flight), depth-2
// parity prefetch, biases in registers. bf16 NHWC intermediates, MFMA 16x16x32.
// B=8, C=64, H=128, W=128.

#define B_ 8
#define C_ 64
#define H_ 128
#define W_ 128
#define HW_ (H_*W_)      // 16384
#define CHW_ (C_*HW_)    // 1048576
#define TOT_ (B_*CHW_)   // 8388608

typedef __attribute__((ext_vector_type(8))) short bfrag;
typedef __attribute__((ext_vector_type(4))) float f4_t;

__device__ inline unsigned short bfr(float f) {
    unsigned int u = __float_as_uint(f);
    u += 0x7fffu + ((u >> 16) & 1u);
    return (unsigned short)(u >> 16);
}
__device__ inline float b2f(unsigned short u) {
    return __uint_as_float(((unsigned int)u) << 16);
}
__device__ inline bfrag packf(float4 a, float4 b) {
    bfrag r;
    r[0]=(short)bfr(a.x); r[1]=(short)bfr(a.y); r[2]=(short)bfr(a.z); r[3]=(short)bfr(a.w);
    r[4]=(short)bfr(b.x); r[5]=(short)bfr(b.y); r[6]=(short)bfr(b.z); r[7]=(short)bfr(b.w);
    return r;
}
__device__ inline ushort4 pack4(float a, float b, float c, float d) {
    ushort4 r; r.x=bfr(a); r.y=bfr(b); r.z=bfr(c); r.w=bfr(d); return r;
}
__device__ inline unsigned int relu2(unsigned int w) {
    unsigned int lo = (w & 0x8000u) ? 0u : (w & 0xffffu);
    unsigned int hi = (w & 0x80000000u) ? 0u : (w & 0xffff0000u);
    return lo | hi;
}
__device__ inline uint4 relu8(uint4 v) {
    v.x = relu2(v.x); v.y = relu2(v.y); v.z = relu2(v.z); v.w = relu2(v.w);
    return v;
}
// LDS-only barrier: drain LDS ops, do NOT drain vmem (prefetch stays in flight)
#define LDS_BARRIER() asm volatile("s_waitcnt lgkmcnt(0)\n\ts_barrier" ::: "memory")

#define MFMA __builtin_amdgcn_mfma_f32_16x16x32_bf16

// x NCHW fp32 -> x2 NHWC bf16 ; y NCHW fp32 -> y2 NHWC fp32
__global__ void k_prep(const float* __restrict__ x, const float* __restrict__ y,
                       float* __restrict__ y2, unsigned short* __restrict__ x2) {
    __shared__ float t[64][65];
    int blk = blockIdx.x;
    int isx = blk >> 11; blk &= 2047;
    int b = blk >> 8, hw0 = (blk & 255) * 64;
    int cq = threadIdx.x >> 6, lo = threadIdx.x & 63;
    const float* ip = (isx ? x : y) + (size_t)b * CHW_;
#pragma unroll
    for (int p = 0; p < 16; p++) {
        int c = p * 4 + cq;
        t[c][lo] = ip[(size_t)c * HW_ + hw0 + lo];
    }
    __syncthreads();
    if (isx) {
        unsigned short* op = x2 + (size_t)b * CHW_;
#pragma unroll
        for (int p = 0; p < 16; p++) {
            int hw = p * 4 + cq;
            op[(size_t)(hw0 + hw) * 64 + lo] = bfr(t[lo][hw]);
        }
    } else {
        float* op = y2 + (size_t)b * CHW_;
#pragma unroll
        for (int p = 0; p < 16; p++) {
            int hw = p * 4 + cq;
            op[(size_t)(hw0 + hw) * 64 + lo] = t[lo][hw];
        }
    }
}

// sum 4 fp32 NHWC dir buffers -> out NCHW fp32
__global__ void k_tb(const float* __restrict__ i0, const float* __restrict__ i1,
                     const float* __restrict__ i2, const float* __restrict__ i3,
                     float* __restrict__ outp) {
    __shared__ float t[64][65];
    int blk = blockIdx.x;
    int b = blk >> 8, hw0 = (blk & 255) * 64;
    int cq = threadIdx.x >> 6, lo = threadIdx.x & 63;
    size_t bb = (size_t)b * CHW_;
#pragma unroll
    for (int p = 0; p < 16; p++) {
        int hw = p * 4 + cq;
        size_t s = bb + (size_t)(hw0 + hw) * 64 + lo;
        t[hw][lo] = i0[s] + i1[s] + i2[s] + i3[s];
    }
    __syncthreads();
    float* op = outp + bb;
#pragma unroll
    for (int p = 0; p < 16; p++) {
        int c = p * 4 + cq;
        op[(size_t)c * HW_ + hw0 + lo] = t[lo][c];
    }
}

struct PFr { uint4 x0, x1; float4 y0, y1, y2, y3; };

// Row scans: grid 128 = s(2) x b(8) x wb(8 of width 16). 1 wave/block,
// NO barriers, depth-2 parity prefetch.
__global__ __launch_bounds__(64) void k_rowscan(
        const unsigned short* __restrict__ x2, const float* __restrict__ y2,
        const float* __restrict__ Wc, const float* __restrict__ bc,
        unsigned short* __restrict__ hs2, unsigned short* __restrict__ hn2) {
    int bid = blockIdx.x;
    int s = bid >> 6, b = (bid >> 3) & 7, wb = bid & 7;
    int w0 = wb * 16;
    int lane = threadIdx.x, q = lane >> 4, n = lane & 15;
    int ka = s ? 8 : 0, kb = ka + 1;

    bfrag WaF[4][2], WbF[4][2];
#pragma unroll
    for (int mt = 0; mt < 4; mt++)
#pragma unroll
        for (int kc = 0; kc < 2; kc++) {
            const float* wp = Wc + (size_t)(ka * 64 + mt * 16 + n) * 64 + kc * 32 + q * 8;
            WaF[mt][kc] = packf(*(const float4*)wp, *(const float4*)(wp + 4));
            const float* wq2 = Wc + (size_t)(kb * 64 + mt * 16 + n) * 64 + kc * 32 + q * 8;
            WbF[mt][kc] = packf(*(const float4*)wq2, *(const float4*)(wq2 + 4));
        }
    f4_t cA[4], cB[4];
#pragma unroll
    for (int mt = 0; mt < 4; mt++) {
        float4 t0 = *(const float4*)&bc[ka * 64 + mt * 16 + q * 4];
        float4 t1 = *(const float4*)&bc[kb * 64 + mt * 16 + q * 4];
        cA[mt] = f4_t{t0.x, t0.y, t0.z, t0.w};
        cB[mt] = f4_t{t1.x, t1.y, t1.z, t1.w};
    }

    const unsigned short* xb = x2 + (size_t)b * CHW_;
    const float* yb = y2 + (size_t)b * CHW_;
    unsigned short* dT = (s ? hn2 : hs2) + (size_t)b * CHW_;

    __shared__ __align__(16) unsigned short stt[2][16][72];

    auto loadPF = [&](int i, PFr& pf) {
        int xrow = s ? 127 - i : i;
        int yrow = s ? xrow + 1 : xrow - 1;
        const unsigned short* sp = xb + (size_t)(xrow * 128 + w0 + n) * 64 + q * 8;
        pf.x0 = *(const uint4*)sp;
        pf.x1 = *(const uint4*)(sp + 32);
        const float* yp = yb + (size_t)(yrow * 128 + w0 + n) * 64;
        pf.y0 = *(const float4*)&yp[q * 4];
        pf.y1 = *(const float4*)&yp[16 + q * 4];
        pf.y2 = *(const float4*)&yp[32 + q * 4];
        pf.y3 = *(const float4*)&yp[48 + q * 4];
    };

    // init row0: h0 = x[row0] (north: relu'd)
    int row0 = s ? 127 : 0;
    {
        const unsigned short* sp = xb + (size_t)(row0 * 128 + w0 + n) * 64 + q * 16;
        uint4 v0 = *(const uint4*)sp;
        uint4 v1 = *(const uint4*)(sp + 8);
        if (s) { v0 = relu8(v0); v1 = relu8(v1); }
        *(uint4*)&stt[0][n][q * 16] = v0;
        *(uint4*)&stt[0][n][q * 16 + 8] = v1;
        unsigned short* op = dT + (size_t)(row0 * 128 + w0 + n) * 64 + q * 16;
        *(uint4*)op = v0;
        *(uint4*)(op + 8) = v1;
    }

    PFr pf1, pf0;
    loadPF(1, pf1);
    loadPF(2, pf0);

    auto body = [&](int i, PFr& pf) {
        int row = s ? 127 - i : i;
        int rd = (i - 1) & 1, wr = i & 1;
        // consume prefetched
        bfrag fa0 = *(const bfrag*)&pf.x0;
        bfrag fa1 = *(const bfrag*)&pf.x1;
        float4 yl[4] = {pf.y0, pf.y1, pf.y2, pf.y3};
        // reissue for i+2 (loads stay in flight across iterations)
        if (i + 2 < 128) loadPF(i + 2, pf);
        // state frags
        bfrag fb0 = *(const bfrag*)&stt[rd][n][q * 8];
        bfrag fb1 = *(const bfrag*)&stt[rd][n][32 + q * 8];
        f4_t DA[4], DB[4];
#pragma unroll
        for (int mt = 0; mt < 4; mt++) {
            DA[mt] = MFMA(WaF[mt][0], fa0, cA[mt], 0, 0, 0);
            DA[mt] = MFMA(WaF[mt][1], fa1, DA[mt], 0, 0, 0);
            DB[mt] = MFMA(WbF[mt][0], fb0, cB[mt], 0, 0, 0);
            DB[mt] = MFMA(WbF[mt][1], fb1, DB[mt], 0, 0, 0);
        }
#pragma unroll
        for (int mt = 0; mt < 4; mt++) {
            float yv[4] = {yl[mt].x, yl[mt].y, yl[mt].z, yl[mt].w};
            float h[4];
#pragma unroll
            for (int r = 0; r < 4; r++)
                h[r] = fmaxf(DA[mt][r] + DB[mt][r] * yv[r], 0.f);
            ushort4 pk = pack4(h[0], h[1], h[2], h[3]);
            *(ushort4*)&stt[wr][n][mt * 16 + q * 4] = pk;
            *(ushort4*)&dT[(size_t)(row * 128 + w0 + n) * 64 + mt * 16 + q * 4] = pk;
        }
    };

    for (int i = 1; i < 128; i += 2) {
        body(i, pf1);
        if (i + 1 < 128) body(i + 1, pf0);
    }
}

struct PFc { uint4 b0, b1; float4 yr0, yr1, yr2, yr3, ys0, ys1, ys2, ys3; };

// Col scans: grid 32 = d(4) x b(8). 512 threads = 8 waves; wave w owns rows
// [16w,16w+16). LDS shift coupling, raw lgkm-only barrier, depth-2 prefetch.
__global__ __launch_bounds__(512) void k_colscan(
        const float* __restrict__ y2,
        const unsigned short* __restrict__ hs2, const unsigned short* __restrict__ hn2,
        const float* __restrict__ Wc, const float* __restrict__ bc,
        const float* __restrict__ gam,
        float* __restrict__ outD) {
    int bid = blockIdx.x;
    int d = bid >> 3, b = bid & 7;
    int tid = threadIdx.x;
    int wave = tid >> 6, lane = tid & 63, q = lane >> 4, n = lane & 15;
    int row = wave * 16 + n;
    int down = (d < 2) ? 1 : 0;
    int flip = d & 1;
    const unsigned short* base2 = ((d < 2) ? hs2 : hn2) + (size_t)b * CHW_;
    int kt, ka, kb;
    if (d == 0)      { kt = 2;  ka = 3;  kb = 4;  }
    else if (d == 1) { kt = 5;  ka = 6;  kb = 7;  }
    else if (d == 2) { kt = 10; ka = 11; kb = 12; }
    else             { kt = 13; ka = 14; kb = 15; }
    float g = gam[d];

    bfrag WA[4][2], WB[4][2], WT[4][2];
#pragma unroll
    for (int mt = 0; mt < 4; mt++)
#pragma unroll
        for (int kc = 0; kc < 2; kc++) {
            const float* wa = Wc + (size_t)(ka * 64 + mt * 16 + n) * 64 + kc * 32 + q * 8;
            const float* wb = Wc + (size_t)(kb * 64 + mt * 16 + n) * 64 + kc * 32 + q * 8;
            const float* wt = Wc + (size_t)(kt * 64 + mt * 16 + n) * 64 + kc * 32 + q * 8;
            WA[mt][kc] = packf(*(const float4*)wa, *(const float4*)(wa + 4));
            WB[mt][kc] = packf(*(const float4*)wb, *(const float4*)(wb + 4));
            WT[mt][kc] = packf(*(const float4*)wt, *(const float4*)(wt + 4));
        }
    f4_t cA[4], cB[4], cT[4];
#pragma unroll
    for (int mt = 0; mt < 4; mt++) {
        float4 t0 = *(const float4*)&bc[ka * 64 + mt * 16 + q * 4];
        float4 t1 = *(const float4*)&bc[kb * 64 + mt * 16 + q * 4];
        float4 t2 = *(const float4*)&bc[kt * 64 + mt * 16 + q * 4];
        cA[mt] = f4_t{t0.x, t0.y, t0.z, t0.w};
        cB[mt] = f4_t{t1.x, t1.y, t1.z, t1.w};
        cT[mt] = f4_t{t2.x, t2.y, t2.z, t2.w};
    }

    const float* yB = y2 + (size_t)b * CHW_;
    float* oB = outD + (size_t)d * TOT_ + (size_t)b * CHW_;

    __shared__ __align__(16) unsigned short stt[2][130][72];  // +1 zero pad per end

    for (int idx = tid; idx < 2 * 2 * 72; idx += 512) {
        int buf = idx / 144, hi = (idx / 72) & 1, t = idx % 72;
        stt[buf][hi ? 129 : 0][t] = 0;
    }

    // ---- j = 0 : c0 = relu(base col0)
    int c0 = flip ? 127 : 0;
    {
        const unsigned short* sp = base2 + (size_t)(row * 128 + c0) * 64 + q * 16;
        uint4 v0 = relu8(*(const uint4*)sp);
        uint4 v1 = relu8(*(const uint4*)(sp + 8));
        *(uint4*)&stt[0][row + 1][q * 16] = v0;
        *(uint4*)&stt[0][row + 1][q * 16 + 8] = v1;
        float* op = oB + (size_t)(row * 128 + c0) * 64 + q * 16;
        unsigned int w8[8] = {v0.x, v0.y, v0.z, v0.w, v1.x, v1.y, v1.z, v1.w};
#pragma unroll
        for (int t = 0; t < 8; t++) {
            op[2 * t]     = b2f((unsigned short)(w8[t] & 0xffffu));
            op[2 * t + 1] = b2f((unsigned short)(w8[t] >> 16));
        }
    }

    int rsh = row + (down ? -1 : 1);
    rsh = rsh < 0 ? 0 : (rsh > 127 ? 127 : rsh);
    int srow = down ? row : row + 2;   // shifted-state LDS index (incl. +1 pad)
    float gT = (down ? (row == 0) : (row == 127)) ? 0.f : g;

    auto loadPF = [&](int j, PFc& pf) {
        int cj = flip ? 127 - j : j;
        int yc = flip ? 128 - j : j - 1;
        const unsigned short* sp = base2 + (size_t)(row * 128 + cj) * 64 + q * 8;
        pf.b0 = *(const uint4*)sp;
        pf.b1 = *(const uint4*)(sp + 32);
        const float* yp = yB + (size_t)(row * 128 + yc) * 64;
        const float* yps = yB + (size_t)(rsh * 128 + yc) * 64;
        pf.yr0 = *(const float4*)&yp[q * 4];
        pf.yr1 = *(const float4*)&yp[16 + q * 4];
        pf.yr2 = *(const float4*)&yp[32 + q * 4];
        pf.yr3 = *(const float4*)&yp[48 + q * 4];
        pf.ys0 = *(const float4*)&yps[q * 4];
        pf.ys1 = *(const float4*)&yps[16 + q * 4];
        pf.ys2 = *(const float4*)&yps[32 + q * 4];
        pf.ys3 = *(const float4*)&yps[48 + q * 4];
    };

    PFc pf1, pf0;
    loadPF(1, pf1);
    loadPF(2, pf0);
    LDS_BARRIER();   // stt[0] state visible to all waves

    auto body = [&](int j, PFc& pf) {
        int cj = flip ? 127 - j : j;
        int rd = (j - 1) & 1, wr = j & 1;
        // consume prefetched
        bfrag fa0 = *(const bfrag*)&pf.b0;
        bfrag fa1 = *(const bfrag*)&pf.b1;
        float4 yrl[4] = {pf.yr0, pf.yr1, pf.yr2, pf.yr3};
        float4 ysl[4] = {pf.ys0, pf.ys1, pf.ys2, pf.ys3};
        // reissue for j+2 (stays in flight across the raw barriers)
        if (j + 2 < 128) loadPF(j + 2, pf);
        // state frags
        bfrag fb0 = *(const bfrag*)&stt[rd][row + 1][q * 8];
        bfrag fb1 = *(const bfrag*)&stt[rd][row + 1][32 + q * 8];
        bfrag ft0 = *(const bfrag*)&stt[rd][srow][q * 8];
        bfrag ft1 = *(const bfrag*)&stt[rd][srow][32 + q * 8];

        f4_t DA[4], DB[4], DT[4];
#pragma unroll
        for (int mt = 0; mt < 4; mt++) {
            DA[mt] = MFMA(WA[mt][0], fa0, cA[mt], 0, 0, 0);
            DA[mt] = MFMA(WA[mt][1], fa1, DA[mt], 0, 0, 0);
            DB[mt] = MFMA(WB[mt][0], fb0, cB[mt], 0, 0, 0);
            DB[mt] = MFMA(WB[mt][1], fb1, DB[mt], 0, 0, 0);
            DT[mt] = MFMA(WT[mt][0], ft0, cT[mt], 0, 0, 0);
            DT[mt] = MFMA(WT[mt][1], ft1, DT[mt], 0, 0, 0);
        }
#pragma unroll
        for (int mt = 0; mt < 4; mt++) {
            float yrv[4] = {yrl[mt].x, yrl[mt].y, yrl[mt].z, yrl[mt].w};
            float ysv[4] = {ysl[mt].x, ysl[mt].y, ysl[mt].z, ysl[mt].w};
            float h[4];
#pragma unroll
            for (int r = 0; r < 4; r++)
                h[r] = fmaxf(DA[mt][r] + DB[mt][r] * yrv[r] + gT * DT[mt][r] * ysv[r], 0.f);
            *(ushort4*)&stt[wr][row + 1][mt * 16 + q * 4] = pack4(h[0], h[1], h[2], h[3]);
            *(float4*)&oB[(size_t)(row * 128 + cj) * 64 + mt * 16 + q * 4] =
                make_float4(h[0], h[1], h[2], h[3]);
        }
        LDS_BARRIER();
    };

    for (int j = 1; j < 128; j += 2) {
        body(j, pf1);
        if (j + 1 < 128) body(j + 1, pf0);
    }
}

extern "C" void kernel_launch(void* const* d_in, const int* in_sizes, int n_in,
                              void* d_out, int out_size, void* d_ws, size_t ws_size,
                              hipStream_t stream) {
    const float* x   = (const float*)d_in[0];
    const float* y   = (const float*)d_in[1];
    const float* Wc  = (const float*)d_in[2];
    const float* bc  = (const float*)d_in[3];
    const float* gam = (const float*)d_in[4];
    float* out = (float*)d_out;

    unsigned short* x2 = (unsigned short*)d_ws;
    float* y2 = (float*)d_ws + (size_t)TOT_ / 2;
    unsigned short* hs2 = (unsigned short*)(y2 + (size_t)TOT_);
    unsigned short* hn2 = hs2 + (size_t)TOT_;
    float* outD = (float*)(hn2 + (size_t)TOT_);   // 4 x fp32 dirs

    hipLaunchKernelGGL(k_prep, dim3(4096), dim3(256), 0, stream, x, y, y2, x2);
    hipLaunchKernelGGL(k_rowscan, dim3(128), dim3(64), 0, stream, x2, y2, Wc, bc, hs2, hn2);
    hipLaunchKernelGGL(k_colscan, dim3(32), dim3(512), 0, stream, y2, hs2, hn2, Wc, bc, gam, outD);
    hipLaunchKernelGGL(k_tb, dim3(2048), dim3(256), 0, stream,
                       outD, outD + (size_t)TOT_, outD + 2 * (size_t)TOT_,
                       outD + 3 * (size_t)TOT_, out);
}